// Round 4
// baseline (77.694 us; speedup 1.0000x reference)
//
#include <hip/hip_runtime.h>
#include <cstddef>

typedef __attribute__((ext_vector_type(8))) short short8v;
typedef __attribute__((ext_vector_type(4))) short short4v;
typedef __attribute__((ext_vector_type(4))) float f32x4;

__device__ __forceinline__ unsigned short f2bf(float f) {
    unsigned u = __float_as_uint(f);
    u = (u + 0x7FFFu + ((u >> 16) & 1u)) >> 16;
    return (unsigned short)u;
}

// ---- prep: W[o][d][e][w] fp32 -> Wb frag-stream bf16 ----
// Wb[(g*64+f)*36864 + ks*2048 + nt*512 + lane*8 + j]
//   = bf16( W[o = g*64+nt*16+(lane&15), d = (lane>>4)*8+j, e = 2f+ks/9, w = ks%9] )
// so a wave's A-frag for (ks,nt) is one contiguous 1KB global_load_dwordx4.
__global__ __launch_bounds__(256) void prep_w(const float* __restrict__ w,
                                              unsigned short* __restrict__ wb)
{
    const int g  = blockIdx.x >> 6;
    const int f  = blockIdx.x & 63;
    const int e0 = 2 * f;
    const int tid = threadIdx.x;
    __shared__ unsigned short ls[64 * 580];   // pitch 580 shorts breaks power-of-2 banks

    // phase 1: coalesced-ish read of W[g*64..+63][all d][e0..e0+1][all w], bf16 -> LDS
    #pragma unroll 4
    for (int i = 0; i < 72; ++i) {
        int fl  = tid + i * 256;           // 0..18431 : (o_l,d) x 9 float2
        int od  = fl / 9;
        int f2i = fl - od * 9;
        int o_l = od >> 5;
        int d   = od & 31;
        const float2 v = *reinterpret_cast<const float2*>(
            &w[(size_t)((g * 64 + o_l) * 32 + d) * 1152 + e0 * 9 + f2i * 2]);
        ushort2 h; h.x = f2bf(v.x); h.y = f2bf(v.y);
        *reinterpret_cast<ushort2*>(&ls[o_l * 580 + d * 18 + f2i * 2]) = h;
    }
    __syncthreads();

    // phase 2: gather d-runs per frag element, perfectly-coalesced 16B global writes
    unsigned short* wo = wb + (size_t)(g * 64 + f) * 36864;
    #pragma unroll 2
    for (int i = 0; i < 18; ++i) {
        int oc   = tid + i * 256;          // 0..4607 : (ks, nt, lane)
        int ks   = oc >> 8;
        int nt   = (oc >> 6) & 3;
        int lane = oc & 63;
        int li = lane & 15, hi = lane >> 4;
        int ec = (ks >= 9) ? 1 : 0;
        int w9 = ks - 9 * ec;
        int o_l = nt * 16 + li;
        short8v vv;
        #pragma unroll
        for (int j = 0; j < 8; ++j)
            vv[j] = (short)ls[o_l * 580 + (hi * 8 + j) * 18 + ec * 9 + w9];
        *reinterpret_cast<short8v*>(&wo[(size_t)oc * 8]) = vv;
    }
}

// ---- main: per (b,g,f) 64n x 128t GEMM, K = 576; A from global frag-stream ----
// 128 threads = 2 waves, each wave 64n x 64t (acc 4x4), A prefetched 2 deep.
__global__ __launch_bounds__(128, 3) void lconv_mfma(const float* __restrict__ x,
                                                     const unsigned short* __restrict__ wb,
                                                     float* __restrict__ out)
{
    // XCD-chunked swizzle: the 8 b-blocks sharing one weight slice -> same XCD
    int bid = blockIdx.x;                  // 0..2047
    int c   = (bid & 7) * 256 + (bid >> 3);
    const int b = c & 7;
    const int f = (c >> 3) & 63;
    const int g = c >> 9;
    const int e0 = 2 * f;

    const int tid  = threadIdx.x;
    const int lane = tid & 63;
    const int th   = tid >> 6;       // wave id -> t-half
    const int li   = lane & 15;
    const int hi   = lane >> 4;

    // xs[e][tp][d], pitch 40 shorts (80B = 20 banks -> uniform bank tiling)
    __shared__ __align__(16) unsigned short xs[2 * 136 * 40];   // 21760 B

    // ---- stage x: column loads (4 coalesced dword, lane->t), one b64 LDS write ----
    const int t = tid;                    // 0..127, full t per 128-thread block
    #pragma unroll
    for (int i = 0; i < 16; ++i) {        // i = e*8 + dhi
        int dhi = i & 7;
        int e   = i >> 3;
        const float* xp = &x[(size_t)((b * 128 + g * 32 + dhi * 4) * 128 + (e0 + e)) * 128 + t];
        float v0 = xp[0];
        float v1 = xp[128 * 128];
        float v2 = xp[2 * 128 * 128];
        float v3 = xp[3 * 128 * 128];
        short4v hq;
        hq[0] = (short)f2bf(v0); hq[1] = (short)f2bf(v1);
        hq[2] = (short)f2bf(v2); hq[3] = (short)f2bf(v3);
        *reinterpret_cast<short4v*>(&xs[(e * 136 + t + 4) * 40 + dhi * 4]) = hq;
    }
    // zero pads: tp in {0..3} and {132..135}, all d
    {
        int e  = tid >> 6;
        int r  = (tid >> 3) & 7;
        int dq = tid & 7;
        int tp = (r < 4) ? r : (128 + r);
        short4v z = {0, 0, 0, 0};
        *reinterpret_cast<short4v*>(&xs[(e * 136 + tp) * 40 + dq * 4]) = z;
    }
    __syncthreads();

    const unsigned short* wsl = wb + (size_t)(g * 64 + f) * 36864;

    f32x4 acc[4][4];
    #pragma unroll
    for (int nt = 0; nt < 4; ++nt)
        #pragma unroll
        for (int tt = 0; tt < 4; ++tt)
            acc[nt][tt] = (f32x4){0.f, 0.f, 0.f, 0.f};

    // A-frag ring, 2 iterations ahead (L2 latency cover); full unroll -> static idx
    short8v A[3][4];
    #pragma unroll
    for (int p = 0; p < 2; ++p)
        #pragma unroll
        for (int nt = 0; nt < 4; ++nt)
            A[p][nt] = *reinterpret_cast<const short8v*>(
                &wsl[(size_t)(p * 4 + nt) * 512 + lane * 8]);

    #pragma unroll
    for (int ks = 0; ks < 18; ++ks) {
        const int cur = ks % 3;
        if (ks < 16) {
            const int ld = (ks + 2) % 3;
            #pragma unroll
            for (int nt = 0; nt < 4; ++nt)
                A[ld][nt] = *reinterpret_cast<const short8v*>(
                    &wsl[(size_t)((ks + 2) * 4 + nt) * 512 + lane * 8]);
        }
        const int ec = (ks >= 9) ? 1 : 0;
        const int w9 = ks - 9 * ec;

        short8v Bf[4];
        #pragma unroll
        for (int tt = 0; tt < 4; ++tt) {
            int tp = th * 64 + tt * 16 + li + w9;
            Bf[tt] = *reinterpret_cast<const short8v*>(
                &xs[(ec * 136 + tp) * 40 + hi * 8]);
        }
        #pragma unroll
        for (int nt = 0; nt < 4; ++nt)
            #pragma unroll
            for (int tt = 0; tt < 4; ++tt)
                acc[nt][tt] = __builtin_amdgcn_mfma_f32_16x16x32_bf16(
                    A[cur][nt], Bf[tt], acc[nt][tt], 0, 0, 0);
    }

    // ---- epilogue: LeakyReLU + store (C: col=lane&15 -> t, row=(lane>>4)*4+j -> n) ----
    #pragma unroll
    for (int nt = 0; nt < 4; ++nt) {
        #pragma unroll
        for (int tt = 0; tt < 4; ++tt) {
            #pragma unroll
            for (int j = 0; j < 4; ++j) {
                float v = acc[nt][tt][j];
                v = (v >= 0.f) ? v : 0.01f * v;
                int n  = nt * 16 + hi * 4 + j;
                int tc = th * 64 + tt * 16 + li;
                out[(((size_t)(b * 256 + g * 64 + n)) * 64 + f) * 128 + tc] = v;
            }
        }
    }
}

extern "C" void kernel_launch(void* const* d_in, const int* in_sizes, int n_in,
                              void* d_out, int out_size, void* d_ws, size_t ws_size,
                              hipStream_t stream)
{
    const float* x = (const float*)d_in[0];           // (8,128,128,128) fp32
    const float* w = (const float*)d_in[1];           // (256,32,128,9) fp32
    float* out = (float*)d_out;                       // (8,256,64,128) fp32
    unsigned short* wb = (unsigned short*)d_ws;       // 4*64*36864 bf16 = 18.9 MB

    hipLaunchKernelGGL(prep_w, dim3(256), dim3(256), 0, stream, w, wb);
    hipLaunchKernelGGL(lconv_mfma, dim3(2048), dim3(128), 0, stream, x, wb, out);
}

// Round 5
// 51.651 us; speedup vs baseline: 1.5042x; 1.5042x over previous
//
#include <hip/hip_runtime.h>
#include <cstddef>

typedef __attribute__((ext_vector_type(8))) short short8v;
typedef __attribute__((ext_vector_type(4))) short short4v;
typedef __attribute__((ext_vector_type(4))) float f32x4;

__device__ __forceinline__ unsigned short f2bf(float f) {
    unsigned u = __float_as_uint(f);
    u = (u + 0x7FFFu + ((u >> 16) & 1u)) >> 16;
    return (unsigned short)u;
}

// ---- prep (verified in R3): W[o][d][e][w] fp32 -> Wb[g][e][n][w*32+d] bf16 ----
__global__ __launch_bounds__(256) void prep_w(const float* __restrict__ w,
                                              unsigned short* __restrict__ wb)
{
    const int o   = blockIdx.x;      // 0..255
    const int tid = threadIdx.x;
    __shared__ unsigned short ls[36864];   // 72 KiB
    const float* wo = w + (size_t)o * 36864;

    for (int i = 0; i < 36; ++i) {
        int idx4 = tid + i * 256;
        float4 v = reinterpret_cast<const float4*>(wo)[idx4];
        int f0 = idx4 * 4;
        int d  = f0 / 1152;
        int sw = (d & 31) << 1;
        int s0 = f0 ^ sw;
        ushort2 p0; p0.x = f2bf(v.x); p0.y = f2bf(v.y);
        ushort2 p1; p1.x = f2bf(v.z); p1.y = f2bf(v.w);
        *reinterpret_cast<ushort2*>(&ls[s0])     = p0;
        *reinterpret_cast<ushort2*>(&ls[s0 ^ 2]) = p1;
    }
    __syncthreads();

    const int g = o >> 6, n = o & 63;
    for (int i = 0; i < 18; ++i) {
        int c  = tid + i * 256;
        int q0 = c * 8;
        int e  = q0 / 288;
        int r  = q0 - e * 288;
        int wi = r >> 5;
        int d0 = r & 31;
        short8v vv;
        #pragma unroll
        for (int j = 0; j < 8; ++j) {
            int d = d0 + j;
            int fq = 1152 * d + 9 * e + wi;
            vv[j] = (short)ls[fq ^ ((d & 31) << 1)];
        }
        size_t oi = (((size_t)(g * 128 + e) * 64 + n) * 288 + (size_t)r);
        *reinterpret_cast<short8v*>(&wb[oi]) = vv;
    }
}

// ---- main: block = (bp, g, f) covering 2 batches x 64n x 128t; 4 waves,
//      wave = (b = bp*2 + (w&1), t-half = w>>1), tile 64n x 64t, acc 4x4.
__global__ __launch_bounds__(256, 2) void lconv_mfma(const float* __restrict__ x,
                                                     const unsigned short* __restrict__ wb,
                                                     float* __restrict__ out)
{
    // XCD-chunked swizzle: 4 bp-blocks sharing one (g,f) weight slice -> same XCD
    int bid = blockIdx.x;                       // 0..1023
    int lid = (bid & 7) * 128 + (bid >> 3);
    const int bp = lid & 3;
    const int f  = (lid >> 2) & 63;
    const int g  = lid >> 8;
    const int e0 = 2 * f;

    const int tid  = threadIdx.x;
    const int lane = tid & 63;
    const int wv   = tid >> 6;
    const int bl   = wv & 1;        // which of the 2 staged batches
    const int th   = wv >> 1;       // t-half
    const int li   = lane & 15;
    const int hi   = lane >> 4;

    // xs[bl][tp][d] pitch 40 shorts (80 B: odd-quad stride -> uniform read banks)
    __shared__ __align__(16) unsigned short xs[2 * 136 * 40];   // 21760 B
    __shared__ __align__(16) unsigned short As[64 * 288];       // 36864 B (58.6 KB tot)

    // zero pads once: tp in {0..3, 132..135}, both bl, all d (written before 1st barrier)
    if (tid < 128) {
        int blz = tid >> 6;
        int r   = (tid >> 3) & 7;
        int dq  = tid & 7;
        int tp  = (r < 4) ? r : (128 + r);
        short4v z = {0, 0, 0, 0};
        *reinterpret_cast<short4v*>(&xs[(blz * 136 + tp) * 40 + dq * 4]) = z;
    }

    f32x4 acc[4][4];
    #pragma unroll
    for (int nt = 0; nt < 4; ++nt)
        #pragma unroll
        for (int tt = 0; tt < 4; ++tt)
            acc[nt][tt] = (f32x4){0.f, 0.f, 0.f, 0.f};

    const int t  = tid & 127;       // staging: lane -> t (coalesced)
    const int z  = tid >> 7;

    for (int ec = 0; ec < 2; ++ec) {
        __syncthreads();            // prior-phase reads done before overwrite

        // stage x(ec): column loads (4 coalesced dword over d), one b64 LDS write
        #pragma unroll
        for (int i = 0; i < 8; ++i) {
            int u   = z * 8 + i;            // 0..15 : (bl2, dq)
            int bl2 = u >> 3;
            int dq  = u & 7;
            const float* xp = &x[(size_t)(((bp * 2 + bl2) * 128 + g * 32 + dq * 4) * 128
                                          + (e0 + ec)) * 128 + t];
            float v0 = xp[0];
            float v1 = xp[128 * 128];
            float v2 = xp[2 * 128 * 128];
            float v3 = xp[3 * 128 * 128];
            short4v hq;
            hq[0] = (short)f2bf(v0); hq[1] = (short)f2bf(v1);
            hq[2] = (short)f2bf(v2); hq[3] = (short)f2bf(v3);
            *reinterpret_cast<short4v*>(&xs[(bl2 * 136 + t + 4) * 40 + dq * 4]) = hq;
        }
        // stage A(ec): contiguous 36.9 KB copy (linear, conflict-free)
        {
            const unsigned short* src = wb + (size_t)((g * 128) + e0 + ec) * (64 * 288);
            #pragma unroll
            for (int i = 0; i < 9; ++i) {
                int u = tid + i * 256;
                *reinterpret_cast<short8v*>(&As[u * 8]) =
                    *reinterpret_cast<const short8v*>(&src[u * 8]);
            }
        }
        __syncthreads();

        #pragma unroll
        for (int w9 = 0; w9 < 9; ++w9) {
            short8v Af[4];
            #pragma unroll
            for (int nt = 0; nt < 4; ++nt)
                Af[nt] = *reinterpret_cast<const short8v*>(
                    &As[(nt * 16 + li) * 288 + w9 * 32 + hi * 8]);

            short8v Bf[4];
            #pragma unroll
            for (int tt = 0; tt < 4; ++tt) {
                int tp = th * 64 + tt * 16 + li + w9;
                Bf[tt] = *reinterpret_cast<const short8v*>(
                    &xs[(bl * 136 + tp) * 40 + hi * 8]);
            }

            #pragma unroll
            for (int nt = 0; nt < 4; ++nt)
                #pragma unroll
                for (int tt = 0; tt < 4; ++tt)
                    acc[nt][tt] = __builtin_amdgcn_mfma_f32_16x16x32_bf16(
                        Af[nt], Bf[tt], acc[nt][tt], 0, 0, 0);
        }
    }

    // ---- epilogue: LeakyReLU + store (C: col=lane&15 -> t, row=(lane>>4)*4+j -> n) ----
    const int b = bp * 2 + bl;
    #pragma unroll
    for (int nt = 0; nt < 4; ++nt) {
        #pragma unroll
        for (int tt = 0; tt < 4; ++tt) {
            #pragma unroll
            for (int j = 0; j < 4; ++j) {
                float v = acc[nt][tt][j];
                v = (v >= 0.f) ? v : 0.01f * v;
                int n  = nt * 16 + hi * 4 + j;
                int tc = th * 64 + tt * 16 + li;
                out[(((size_t)(b * 256 + g * 64 + n)) * 64 + f) * 128 + tc] = v;
            }
        }
    }
}

extern "C" void kernel_launch(void* const* d_in, const int* in_sizes, int n_in,
                              void* d_out, int out_size, void* d_ws, size_t ws_size,
                              hipStream_t stream)
{
    const float* x = (const float*)d_in[0];           // (8,128,128,128) fp32
    const float* w = (const float*)d_in[1];           // (256,32,128,9) fp32
    float* out = (float*)d_out;                       // (8,256,64,128) fp32
    unsigned short* wb = (unsigned short*)d_ws;       // 4*128*64*288 bf16 = 18.9 MB

    hipLaunchKernelGGL(prep_w, dim3(256), dim3(256), 0, stream, w, wb);
    hipLaunchKernelGGL(lconv_mfma, dim3(1024), dim3(256), 0, stream, x, wb, out);
}